// Round 1
// baseline (63.425 us; speedup 1.0000x reference)
//
#include <hip/hip_runtime.h>

// CostVolume (gwc): out[b,g,d,h,w] = (w>=d) ? mean_c( L[b,g*8+c,h,w] * R[b,g*8+c,h,w-d] ) : 0
// B=4, C=320, G=40, Cg=8, D=48, H=64, W=128. Output [4,40,48,64,128] fp32 (252 MB) -> store-BW bound.
//
// One block per (b,g,h). Stage L row (8x128) and R row (8x[48 zeros + 128]) in LDS;
// zero left-pad implements the w>=d mask branch-free. Each thread computes a 4w x 8d tile:
// per channel, 3x ds_read_b128 (12-float R window, alignment offset compile-time const)
// + 1x ds_read_b128 for L, 32 FMAs. float4 coalesced stores.

#define NG 40
#define ND 48
#define NCG 8
#define NH 64
#define NW 128

__global__ __launch_bounds__(192) void cost_volume_kernel(
    const float* __restrict__ left, const float* __restrict__ right,
    float* __restrict__ out)
{
    __shared__ float Ls[NCG][NW];      // 4 KB
    __shared__ float Rs[NCG][176];     // 5.5 KB, [0,48) zeros, [48,176) = R row

    const int tid = threadIdx.x;
    const int blk = blockIdx.x;
    const int h = blk & 63;
    const int g = (blk >> 6) % NG;
    const int b = blk / (NG * NH);

    // zero the left pad: 8*48 floats = 96 float4
    if (tid < 96) {
        int c = tid / 12;
        int j = (tid % 12) * 4;
        *(float4*)&Rs[c][j] = make_float4(0.f, 0.f, 0.f, 0.f);
    }

    // stage L and R rows: 256 float4 each, coalesced
    const size_t inbase = (((size_t)b * (NG * NCG) + (size_t)g * NCG) * NH + h) * NW;
    for (int i = tid; i < 256; i += 192) {
        int c  = i >> 5;
        int w4 = (i & 31) << 2;
        const size_t off = inbase + (size_t)c * (NH * NW) + w4;
        *(float4*)&Ls[c][w4]      = *(const float4*)&left[off];
        *(float4*)&Rs[c][48 + w4] = *(const float4*)&right[off];
    }
    __syncthreads();

    const int wt = tid & 31;   // 32 w-tiles of 4
    const int dt = tid >> 5;   // 6 d-tiles of 8
    const int w0 = wt << 2;
    const int d0 = dt << 3;
    const int xa = w0 - d0 + 40;   // ≡ 0 (mod 4): aligned b128 window base, in [0,164]

    float acc[8][4];
#pragma unroll
    for (int d = 0; d < 8; ++d)
#pragma unroll
        for (int w = 0; w < 4; ++w) acc[d][w] = 0.f;

#pragma unroll
    for (int c = 0; c < NCG; ++c) {
        float4 r0 = *(const float4*)&Rs[c][xa];
        float4 r1 = *(const float4*)&Rs[c][xa + 4];
        float4 r2 = *(const float4*)&Rs[c][xa + 8];
        float4 l  = *(const float4*)&Ls[c][w0];
        float rw[12] = {r0.x, r0.y, r0.z, r0.w,
                        r1.x, r1.y, r1.z, r1.w,
                        r2.x, r2.y, r2.z, r2.w};
        float lw[4] = {l.x, l.y, l.z, l.w};
        // out(d0+d, w0+w) needs Rs[c][(w0+w)-(d0+d)+48] -> rw[w-d+8], static index in [1,11]
#pragma unroll
        for (int d = 0; d < 8; ++d) {
#pragma unroll
            for (int w = 0; w < 4; ++w) {
                acc[d][w] = fmaf(lw[w], rw[w - d + 8], acc[d][w]);
            }
        }
    }

    // store: 8 float4 rows, coalesced across lanes
    const size_t obase = ((((size_t)b * NG + g) * ND + d0) * NH + h) * NW + w0;
#pragma unroll
    for (int d = 0; d < 8; ++d) {
        float4 o = make_float4(acc[d][0] * 0.125f, acc[d][1] * 0.125f,
                               acc[d][2] * 0.125f, acc[d][3] * 0.125f);
        *(float4*)&out[obase + (size_t)d * (NH * NW)] = o;
    }
}

extern "C" void kernel_launch(void* const* d_in, const int* in_sizes, int n_in,
                              void* d_out, int out_size, void* d_ws, size_t ws_size,
                              hipStream_t stream) {
    const float* left  = (const float*)d_in[0];   // left_gwc  [4,320,64,128]
    const float* right = (const float*)d_in[1];   // right_gwc [4,320,64,128]
    float* out = (float*)d_out;                   // [4,40,48,64,128]
    const int grid = 4 * NG * NH;                 // 10240 blocks
    cost_volume_kernel<<<grid, 192, 0, stream>>>(left, right, out);
}

// Round 3
// 63.266 us; speedup vs baseline: 1.0025x; 1.0025x over previous
//
#include <hip/hip_runtime.h>

// CostVolume (gwc): out[b,g,d,h,w] = (w>=d) ? mean_c( L[b,g*8+c,h,w] * R[b,g*8+c,h,w-d] ) : 0
// B=4, C=320, G=40, Cg=8, D=48, H=64, W=128. Output [4,40,48,64,128] fp32 (252 MB) -> store-BW bound.
//
// R2: same as R1 (two adjacent h rows per block for 1 KB contiguous load/store runs,
// nontemporal stores) with the nontemporal store done via a clang ext_vector float4
// (the builtin rejects HIP_vector_type pointers).

#define NG 40
#define ND 48
#define NCG 8
#define NH 64
#define NW 128

typedef float f32x4 __attribute__((ext_vector_type(4)));

__global__ __launch_bounds__(384) void cost_volume_kernel(
    const float* __restrict__ left, const float* __restrict__ right,
    float* __restrict__ out)
{
    __shared__ float Ls[2][NCG][NW];      // 8 KB
    __shared__ float Rs[2][NCG][176];     // 11 KB, [0,48) zeros, [48,176) = R row

    const int tid = threadIdx.x;
    const int blk = blockIdx.x;
    const int h2 = blk & 31;              // h-pair index
    const int g  = (blk >> 5) % NG;
    const int b  = blk / (NG * 32);

    // zero the left pads: 2*8*48 floats = 192 float4
    if (tid < 192) {
        int hr = tid / 96;
        int r  = tid % 96;
        int c  = r / 12;
        int j  = (r % 12) * 4;
        *(float4*)&Rs[hr][c][j] = make_float4(0.f, 0.f, 0.f, 0.f);
    }

    // stage L and R row-pairs: rows h0,h0+1 are contiguous (256 floats per channel)
    // 512 float4 per input over 384 threads, coalesced
    const int h0 = h2 << 1;
    const size_t inbase = (((size_t)b * (NG * NCG) + (size_t)g * NCG) * NH + h0) * NW;
    for (int i = tid; i < 512; i += 384) {
        int c   = i >> 6;          // channel
        int rem = i & 63;          // float4 within the 2-row pair
        int hr  = rem >> 5;
        int w4  = (rem & 31) << 2;
        const size_t off = inbase + (size_t)c * (NH * NW) + (size_t)rem * 4;
        *(float4*)&Ls[hr][c][w4]      = *(const float4*)&left[off];
        *(float4*)&Rs[hr][c][48 + w4] = *(const float4*)&right[off];
    }
    __syncthreads();

    const int hh = tid / 192;      // which h row this thread computes
    const int t  = tid % 192;
    const int wt = t & 31;         // 32 w-tiles of 4
    const int dt = t >> 5;         // 6 d-tiles of 8
    const int w0 = wt << 2;
    const int d0 = dt << 3;
    const int xa = w0 - d0 + 40;   // ≡ 0 (mod 4): aligned b128 window base, in [0,164]

    float acc[8][4];
#pragma unroll
    for (int d = 0; d < 8; ++d)
#pragma unroll
        for (int w = 0; w < 4; ++w) acc[d][w] = 0.f;

#pragma unroll
    for (int c = 0; c < NCG; ++c) {
        float4 r0 = *(const float4*)&Rs[hh][c][xa];
        float4 r1 = *(const float4*)&Rs[hh][c][xa + 4];
        float4 r2 = *(const float4*)&Rs[hh][c][xa + 8];
        float4 l  = *(const float4*)&Ls[hh][c][w0];
        float rw[12] = {r0.x, r0.y, r0.z, r0.w,
                        r1.x, r1.y, r1.z, r1.w,
                        r2.x, r2.y, r2.z, r2.w};
        float lw[4] = {l.x, l.y, l.z, l.w};
        // out(d0+d, w0+w) needs Rs[hh][c][(w0+w)-(d0+d)+48] -> rw[w-d+8], static index in [1,11]
#pragma unroll
        for (int d = 0; d < 8; ++d) {
#pragma unroll
            for (int w = 0; w < 4; ++w) {
                acc[d][w] = fmaf(lw[w], rw[w - d + 8], acc[d][w]);
            }
        }
    }

    // store: 8 float4 rows per thread, nontemporal (zero-reuse stream), coalesced across lanes
    const size_t obase = ((((size_t)b * NG + g) * ND + d0) * NH + (h0 + hh)) * NW + w0;
#pragma unroll
    for (int d = 0; d < 8; ++d) {
        f32x4 o;
        o.x = acc[d][0] * 0.125f;
        o.y = acc[d][1] * 0.125f;
        o.z = acc[d][2] * 0.125f;
        o.w = acc[d][3] * 0.125f;
        __builtin_nontemporal_store(o, (f32x4*)&out[obase + (size_t)d * (NH * NW)]);
    }
}

extern "C" void kernel_launch(void* const* d_in, const int* in_sizes, int n_in,
                              void* d_out, int out_size, void* d_ws, size_t ws_size,
                              hipStream_t stream) {
    const float* left  = (const float*)d_in[0];   // left_gwc  [4,320,64,128]
    const float* right = (const float*)d_in[1];   // right_gwc [4,320,64,128]
    float* out = (float*)d_out;                   // [4,40,48,64,128]
    const int grid = 4 * NG * 32;                 // 5120 blocks (2 h rows each)
    cost_volume_kernel<<<grid, 384, 0, stream>>>(left, right, out);
}